// Round 2
// baseline (203.271 us; speedup 1.0000x reference)
//
#include <hip/hip_runtime.h>
#include <hip/hip_bf16.h>

// LightGCN: two rounds of edge aggregation.
//   h[i]   = sum_{e: dst[e]==i} x[src[e]]
//   out[i] = sum_{e: dst[e]==i} relu(h)[src[e]]
//
// Round 14 (single-pass partition; aggregate untouched from R12):
//   R12 (306 blk / 16-iter chains) and R13 (153 blk / 32-iter chains) both
//   landed at ~55 us -> the 3-phase tile structure itself (LDS hist +
//   reserve + place, 12.8KB LDS on EVERY block incl. 3125 convert blocks,
//   4 waves/block, 2 barriers) was the bind, not atomics or write traffic.
//   Replace with: zero-LDS single pass, one device atomicAdd per EDGE on a
//   padded per-bucket cursor (800 atomics/line, memory-side units retire
//   same-address atomics back-to-back ~5-15cy -> ~2-5us worst line), then
//   direct scatter store. 2048 blocks x 2.4 edges/thread = short chains,
//   full occupancy (no LDS, 12 VGPRs).
//   - aggregate: TWO blocks per 64-node bucket (grid 3126), filter to
//     32-node half, counting-sort, one 8-lane group per node. Unchanged.
//   - ReLU folded into pass-1's bf16 write (elementwise, commutes).

#define N_FEAT   64
#define B_SHIFT  6
#define NPB      64
#define CAPB     1024              // edges per bucket (mean 800, +8 sigma)
#define HALF_CAP 512               // edges per 32-node half (mean 400, max~480)
#define NLOC     32                // nodes per aggregate block
#define NB_H     1568              // >= n_buckets (1563)
#define GSTRIDE  32                // one gcur cursor per 128B line
#define PART_BLOCKS 2048

typedef unsigned int u32;
typedef unsigned short u16;
typedef __attribute__((ext_vector_type(8))) unsigned short u16x8;
typedef __attribute__((ext_vector_type(4))) unsigned int u32x4;
typedef __attribute__((ext_vector_type(2))) float f32x2;

__device__ inline u16 f2bf(float f) {          // RTNE
    u32 u = __builtin_bit_cast(u32, f);
    return (u16)((u + 0x7FFFu + ((u >> 16) & 1u)) >> 16);
}

__global__ __launch_bounds__(256) void partition_convert_kernel(
    const float* __restrict__ xf, u16* __restrict__ xb, int n_elems,
    const int* __restrict__ src, const int* __restrict__ dst,
    u32* __restrict__ gcur,        // [n_buckets*GSTRIDE] padded cursors (zeroed)
    u32* __restrict__ bdata,       // [n_buckets*CAPB] packed (dl<<17)|src
    int n_edges, int part_blocks)
{
    const int tid = threadIdx.x;

    if ((int)blockIdx.x >= part_blocks) {      // ---- convert x -> bf16 ----
        int i = (((int)blockIdx.x - part_blocks) * 256 + tid) * 8;
        if (i < n_elems) {
            float4 a = *(const float4*)(xf + i);
            float4 b = *(const float4*)(xf + i + 4);
            u16x8 r;
            r[0]=f2bf(a.x); r[1]=f2bf(a.y); r[2]=f2bf(a.z); r[3]=f2bf(a.w);
            r[4]=f2bf(b.x); r[5]=f2bf(b.y); r[6]=f2bf(b.z); r[7]=f2bf(b.w);
            *(u16x8*)(xb + i) = r;
        }
        return;
    }

    // ---- single-pass partition: one cursor atomic per edge ----
    const int stride = part_blocks * 256;
    for (int e = (int)blockIdx.x * 256 + tid; e < n_edges; e += stride) {
        int d = dst[e];
        int s = src[e];
        u32 b   = (u32)d >> B_SHIFT;
        u32 pos = atomicAdd(&gcur[b * GSTRIDE], 1u);
        if (pos < CAPB)
            bdata[(size_t)b * CAPB + pos] = ((u32)(d & (NPB - 1)) << 17) | (u32)s;
    }
}

// Two blocks per bucket; block owns 32 nodes (half = blockIdx&1).
// Filter bucket edges to our half (LDS append + histogram), counting-sort,
// then one 8-lane group per node gathers & accumulates -- no shuffles.
// pass 0: out_bf[node] = bf16(relu(sum))   pass 1: out_f[node] = sum (fp32)
__global__ __launch_bounds__(256) void aggregate_kernel(
    const u16* __restrict__ xin,
    const u32* __restrict__ gcur,
    const u32* __restrict__ bdata,
    u16* __restrict__ out_bf,
    float* __restrict__ out_f,
    int n_nodes, int pass)
{
    __shared__ u32 ebuf[HALF_CAP];
    __shared__ u32 sorted[HALF_CAP];
    __shared__ u32 lcnt[NLOC];
    __shared__ u32 lpos[NLOC];
    __shared__ int ptr[NLOC + 1];
    __shared__ u32 ecnt;

    const int tid  = threadIdx.x;
    const int B    = blockIdx.x >> 1;
    const int half = blockIdx.x & 1;

    if (tid < NLOC) { lcnt[tid] = 0; lpos[tid] = 0; }
    if (tid == 0) ecnt = 0;
    __syncthreads();

    int cnt = (int)gcur[B * GSTRIDE];
    if (cnt > CAPB) cnt = CAPB;

    // Filter + append + histogram in one sweep over the bucket's edges.
    const u32* bd = bdata + (size_t)B * CAPB;
    for (int j = tid; j < cnt; j += 256) {
        u32 p  = bd[j];
        int dl = (int)(p >> 17);
        if ((dl >> 5) == half) {
            u32 pos = atomicAdd(&ecnt, 1u);
            if (pos < HALF_CAP) {
                ebuf[pos] = p;
                atomicAdd(&lcnt[dl & (NLOC - 1)], 1u);
            }
        }
    }
    __syncthreads();

    if (tid < NLOC) {                    // lanes 0..31: shfl inclusive scan
        int sc = (int)lcnt[tid];
        #pragma unroll
        for (int d = 1; d < NLOC; d <<= 1) {
            int o = __shfl_up(sc, d);
            if (tid >= d) sc += o;
        }
        ptr[tid + 1] = sc;
        if (tid == 0) ptr[0] = 0;
    }
    __syncthreads();

    int en = (int)ecnt; if (en > HALF_CAP) en = HALF_CAP;
    for (int j = tid; j < en; j += 256) {              // place
        u32 p  = ebuf[j];
        int dl = (int)(p >> 17) & (NLOC - 1);
        u32 pos = atomicAdd(&lpos[dl], 1u);
        sorted[ptr[dl] + pos] = p & 0x1FFFFu;
    }
    __syncthreads();

    // One 8-lane group per node: group g of wave w owns local node w*8+g.
    const int w    = tid >> 6;
    const int lane = tid & 63;
    const int grp  = lane >> 3;
    const int sub  = lane & 7;           // 16B chunk of the 128B bf16 row
    const char* xc = (const char*)xin;

    const int nl   = w * 8 + grp;        // 0..31
    const int node = B * NPB + half * NLOC + nl;
    const int s0 = ptr[nl], s1 = ptr[nl + 1];

    f32x2 a0={0.f,0.f}, a1={0.f,0.f}, a2={0.f,0.f}, a3={0.f,0.f};
    for (int j = s0; j < s1; ++j) {      // uniform within group
        u32 s = sorted[j];               // LDS broadcast (8 lanes same addr)
        u32x4 v = *(const u32x4*)(xc + ((size_t)s << 7) + (sub << 4));
        a0 += (f32x2){ __builtin_bit_cast(float, v[0] << 16),
                       __builtin_bit_cast(float, v[0] & 0xFFFF0000u) };
        a1 += (f32x2){ __builtin_bit_cast(float, v[1] << 16),
                       __builtin_bit_cast(float, v[1] & 0xFFFF0000u) };
        a2 += (f32x2){ __builtin_bit_cast(float, v[2] << 16),
                       __builtin_bit_cast(float, v[2] & 0xFFFF0000u) };
        a3 += (f32x2){ __builtin_bit_cast(float, v[3] << 16),
                       __builtin_bit_cast(float, v[3] & 0xFFFF0000u) };
    }

    if (node < n_nodes) {
        if (pass == 0) {                 // 64 lanes x 16B: 8 bf16 rows, relu'd
            u16x8 o;
            o[0]=f2bf(fmaxf(a0.x,0.f)); o[1]=f2bf(fmaxf(a0.y,0.f));
            o[2]=f2bf(fmaxf(a1.x,0.f)); o[3]=f2bf(fmaxf(a1.y,0.f));
            o[4]=f2bf(fmaxf(a2.x,0.f)); o[5]=f2bf(fmaxf(a2.y,0.f));
            o[6]=f2bf(fmaxf(a3.x,0.f)); o[7]=f2bf(fmaxf(a3.y,0.f));
            *(u16x8*)(out_bf + (size_t)node * N_FEAT + sub * 8) = o;
        } else {                         // 64 lanes x 32B: 8 fp32 rows
            float* dp = out_f + (size_t)node * N_FEAT + sub * 8;
            *(float4*)dp       = (float4){a0.x, a0.y, a1.x, a1.y};
            *(float4*)(dp + 4) = (float4){a2.x, a2.y, a3.x, a3.y};
        }
    }
}

extern "C" void kernel_launch(void* const* d_in, const int* in_sizes, int n_in,
                              void* d_out, int out_size, void* d_ws, size_t ws_size,
                              hipStream_t stream) {
    const float* x          = (const float*)d_in[0];
    const int*   edge_index = (const int*)d_in[1];

    const int n_edges = in_sizes[1] / 2;          // (2, N_EDGES) row-major
    const int* src = edge_index;                  // row 0
    const int* dst = edge_index + n_edges;        // row 1

    const int n_nodes   = out_size / N_FEAT;      // 100000
    const int n_buckets = (n_nodes + NPB - 1) >> B_SHIFT;   // 1563
    float* out = (float*)d_out;

    const size_t xb_bytes    = (size_t)out_size * sizeof(u16);             // 12.8 MB
    const size_t hb_bytes    = (size_t)out_size * sizeof(u16);             // 12.8 MB
    const size_t bdata_bytes = (size_t)n_buckets * CAPB * sizeof(u32);     // 6.4 MB
    const size_t gcur_bytes  = (size_t)NB_H * GSTRIDE * sizeof(u32);       // 200 KB

    char* w = (char*)d_ws;
    u16* xb    = (u16*)w;                w += xb_bytes;
    u16* hb    = (u16*)w;                w += hb_bytes;
    u32* bdata = (u32*)w;                w += bdata_bytes;
    u32* gcur  = (u32*)w;

    hipMemsetAsync(gcur, 0, gcur_bytes, stream);

    const int part_blocks = PART_BLOCKS;                     // 2048
    const int conv_blocks = (out_size / 8 + 255) / 256;      // 3125
    partition_convert_kernel<<<part_blocks + conv_blocks, 256, 0, stream>>>(
        x, xb, out_size, src, dst, gcur, bdata, n_edges, part_blocks);

    const int agg_blocks = 2 * n_buckets;                    // 3126
    aggregate_kernel<<<agg_blocks, 256, 0, stream>>>(xb, gcur, bdata, hb, nullptr, n_nodes, 0);
    aggregate_kernel<<<agg_blocks, 256, 0, stream>>>(hb, gcur, bdata, nullptr, out, n_nodes, 1);
}

// Round 3
// 199.560 us; speedup vs baseline: 1.0186x; 1.0186x over previous
//
#include <hip/hip_runtime.h>
#include <hip/hip_bf16.h>

// LightGCN: two rounds of edge aggregation.
//   h[i]   = sum_{e: dst[e]==i} x[src[e]]
//   out[i] = sum_{e: dst[e]==i} relu(h)[src[e]]
//
// Round 15 (XCD-sharded single-pass partition):
//   R14 (per-edge atomic, shared buckets) regressed 55->75us with TWO
//   smoking guns: WRITE_SIZE 37->79MB (cross-XCD false sharing of bdata
//   lines: 8 non-coherent L2s each writing back partial copies of the same
//   64B line) and same-address cursor atomics serializing at the device
//   coherence point from all 8 XCDs. Fix both BY CONSTRUCTION: shard every
//   bucket 8x by blockIdx&7 (the XCD round-robin residue). Each (bucket,
//   shard) has a private cursor + private 192-slot bdata segment -> bdata
//   lines are written by one XCD only (writes coalesce in that L2), and
//   per-cursor atomic depth drops 8x (800->100) with contenders co-located
//   on one XCD. Keeps R14's zero-LDS full-occupancy structure.
//   - aggregate: TWO blocks per 64-node bucket (grid 3126), filter the 8
//     shard segments to our 32-node half, counting-sort, one 8-lane group
//     per node. Only the filter loop changed (walks 8 segments).
//   - ReLU folded into pass-1's bf16 write (elementwise, commutes).

#define N_FEAT   64
#define B_SHIFT  6
#define NPB      64
#define NSH      8                 // shards per bucket (one per XCD residue)
#define CAPS     192               // edges per (bucket,shard): mean 100, +9 sigma
#define HALF_CAP 512               // edges per 32-node half (mean 400, max~480)
#define NLOC     32                // nodes per aggregate block
#define NB_H     1568              // >= n_buckets (1563)
#define GSTRIDE  16                // one gcur cursor per 64B line
#define PART_BLOCKS 2048

typedef unsigned int u32;
typedef unsigned short u16;
typedef __attribute__((ext_vector_type(8))) unsigned short u16x8;
typedef __attribute__((ext_vector_type(4))) unsigned int u32x4;
typedef __attribute__((ext_vector_type(2))) float f32x2;

__device__ inline u16 f2bf(float f) {          // RTNE
    u32 u = __builtin_bit_cast(u32, f);
    return (u16)((u + 0x7FFFu + ((u >> 16) & 1u)) >> 16);
}

__global__ __launch_bounds__(256) void partition_convert_kernel(
    const float* __restrict__ xf, u16* __restrict__ xb, int n_elems,
    const int* __restrict__ src, const int* __restrict__ dst,
    u32* __restrict__ gcur,        // [n_buckets*NSH*GSTRIDE] padded cursors (zeroed)
    u32* __restrict__ bdata,       // [n_buckets*NSH*CAPS] packed (dl<<17)|src
    int n_edges, int part_blocks)
{
    const int tid = threadIdx.x;

    if ((int)blockIdx.x >= part_blocks) {      // ---- convert x -> bf16 ----
        int i = (((int)blockIdx.x - part_blocks) * 256 + tid) * 8;
        if (i < n_elems) {
            float4 a = *(const float4*)(xf + i);
            float4 b = *(const float4*)(xf + i + 4);
            u16x8 r;
            r[0]=f2bf(a.x); r[1]=f2bf(a.y); r[2]=f2bf(a.z); r[3]=f2bf(a.w);
            r[4]=f2bf(b.x); r[5]=f2bf(b.y); r[6]=f2bf(b.z); r[7]=f2bf(b.w);
            *(u16x8*)(xb + i) = r;
        }
        return;
    }

    // ---- single-pass partition, XCD-sharded cursors/segments ----
    const int shard  = (int)blockIdx.x & (NSH - 1);
    const int stride = part_blocks * 256;
    for (int e = (int)blockIdx.x * 256 + tid; e < n_edges; e += stride) {
        int d = dst[e];
        int s = src[e];
        u32 c   = ((u32)d >> B_SHIFT) * NSH + (u32)shard;
        u32 pos = atomicAdd(&gcur[c * GSTRIDE], 1u);
        if (pos < CAPS)
            bdata[(size_t)c * CAPS + pos] = ((u32)(d & (NPB - 1)) << 17) | (u32)s;
    }
}

// Two blocks per bucket; block owns 32 nodes (half = blockIdx&1).
// Filter the bucket's 8 shard segments to our half (LDS append + histogram),
// counting-sort, then one 8-lane group per node gathers & accumulates.
// pass 0: out_bf[node] = bf16(relu(sum))   pass 1: out_f[node] = sum (fp32)
__global__ __launch_bounds__(256) void aggregate_kernel(
    const u16* __restrict__ xin,
    const u32* __restrict__ gcur,
    const u32* __restrict__ bdata,
    u16* __restrict__ out_bf,
    float* __restrict__ out_f,
    int n_nodes, int pass)
{
    __shared__ u32 ebuf[HALF_CAP];
    __shared__ u32 sorted[HALF_CAP];
    __shared__ u32 lcnt[NLOC];
    __shared__ u32 lpos[NLOC];
    __shared__ int ptr[NLOC + 1];
    __shared__ u32 ecnt;

    const int tid  = threadIdx.x;
    const int B    = blockIdx.x >> 1;
    const int half = blockIdx.x & 1;

    if (tid < NLOC) { lcnt[tid] = 0; lpos[tid] = 0; }
    if (tid == 0) ecnt = 0;
    __syncthreads();

    // Filter + append + histogram over the bucket's 8 shard segments.
    for (int sg = 0; sg < NSH; ++sg) {
        const u32 c = (u32)(B * NSH + sg);
        int cnt = (int)gcur[c * GSTRIDE];
        if (cnt > CAPS) cnt = CAPS;
        const u32* bd = bdata + (size_t)c * CAPS;
        for (int j = tid; j < cnt; j += 256) {
            u32 p  = bd[j];
            int dl = (int)(p >> 17);
            if ((dl >> 5) == half) {
                u32 pos = atomicAdd(&ecnt, 1u);
                if (pos < HALF_CAP) {
                    ebuf[pos] = p;
                    atomicAdd(&lcnt[dl & (NLOC - 1)], 1u);
                }
            }
        }
    }
    __syncthreads();

    if (tid < NLOC) {                    // lanes 0..31: shfl inclusive scan
        int sc = (int)lcnt[tid];
        #pragma unroll
        for (int d = 1; d < NLOC; d <<= 1) {
            int o = __shfl_up(sc, d);
            if (tid >= d) sc += o;
        }
        ptr[tid + 1] = sc;
        if (tid == 0) ptr[0] = 0;
    }
    __syncthreads();

    int en = (int)ecnt; if (en > HALF_CAP) en = HALF_CAP;
    for (int j = tid; j < en; j += 256) {              // place
        u32 p  = ebuf[j];
        int dl = (int)(p >> 17) & (NLOC - 1);
        u32 pos = atomicAdd(&lpos[dl], 1u);
        sorted[ptr[dl] + pos] = p & 0x1FFFFu;
    }
    __syncthreads();

    // One 8-lane group per node: group g of wave w owns local node w*8+g.
    const int w    = tid >> 6;
    const int lane = tid & 63;
    const int grp  = lane >> 3;
    const int sub  = lane & 7;           // 16B chunk of the 128B bf16 row
    const char* xc = (const char*)xin;

    const int nl   = w * 8 + grp;        // 0..31
    const int node = B * NPB + half * NLOC + nl;
    const int s0 = ptr[nl], s1 = ptr[nl + 1];

    f32x2 a0={0.f,0.f}, a1={0.f,0.f}, a2={0.f,0.f}, a3={0.f,0.f};
    for (int j = s0; j < s1; ++j) {      // uniform within group
        u32 s = sorted[j];               // LDS broadcast (8 lanes same addr)
        u32x4 v = *(const u32x4*)(xc + ((size_t)s << 7) + (sub << 4));
        a0 += (f32x2){ __builtin_bit_cast(float, v[0] << 16),
                       __builtin_bit_cast(float, v[0] & 0xFFFF0000u) };
        a1 += (f32x2){ __builtin_bit_cast(float, v[1] << 16),
                       __builtin_bit_cast(float, v[1] & 0xFFFF0000u) };
        a2 += (f32x2){ __builtin_bit_cast(float, v[2] << 16),
                       __builtin_bit_cast(float, v[2] & 0xFFFF0000u) };
        a3 += (f32x2){ __builtin_bit_cast(float, v[3] << 16),
                       __builtin_bit_cast(float, v[3] & 0xFFFF0000u) };
    }

    if (node < n_nodes) {
        if (pass == 0) {                 // 64 lanes x 16B: 8 bf16 rows, relu'd
            u16x8 o;
            o[0]=f2bf(fmaxf(a0.x,0.f)); o[1]=f2bf(fmaxf(a0.y,0.f));
            o[2]=f2bf(fmaxf(a1.x,0.f)); o[3]=f2bf(fmaxf(a1.y,0.f));
            o[4]=f2bf(fmaxf(a2.x,0.f)); o[5]=f2bf(fmaxf(a2.y,0.f));
            o[6]=f2bf(fmaxf(a3.x,0.f)); o[7]=f2bf(fmaxf(a3.y,0.f));
            *(u16x8*)(out_bf + (size_t)node * N_FEAT + sub * 8) = o;
        } else {                         // 64 lanes x 32B: 8 fp32 rows
            float* dp = out_f + (size_t)node * N_FEAT + sub * 8;
            *(float4*)dp       = (float4){a0.x, a0.y, a1.x, a1.y};
            *(float4*)(dp + 4) = (float4){a2.x, a2.y, a3.x, a3.y};
        }
    }
}

extern "C" void kernel_launch(void* const* d_in, const int* in_sizes, int n_in,
                              void* d_out, int out_size, void* d_ws, size_t ws_size,
                              hipStream_t stream) {
    const float* x          = (const float*)d_in[0];
    const int*   edge_index = (const int*)d_in[1];

    const int n_edges = in_sizes[1] / 2;          // (2, N_EDGES) row-major
    const int* src = edge_index;                  // row 0
    const int* dst = edge_index + n_edges;        // row 1

    const int n_nodes   = out_size / N_FEAT;      // 100000
    const int n_buckets = (n_nodes + NPB - 1) >> B_SHIFT;   // 1563
    float* out = (float*)d_out;

    const size_t xb_bytes    = (size_t)out_size * sizeof(u16);                 // 12.8 MB
    const size_t hb_bytes    = (size_t)out_size * sizeof(u16);                 // 12.8 MB
    const size_t bdata_bytes = (size_t)n_buckets * NSH * CAPS * sizeof(u32);   // 9.6 MB
    const size_t gcur_bytes  = (size_t)NB_H * NSH * GSTRIDE * sizeof(u32);     // 800 KB

    char* w = (char*)d_ws;
    u16* xb    = (u16*)w;                w += xb_bytes;
    u16* hb    = (u16*)w;                w += hb_bytes;
    u32* bdata = (u32*)w;                w += bdata_bytes;
    u32* gcur  = (u32*)w;

    hipMemsetAsync(gcur, 0, gcur_bytes, stream);

    const int part_blocks = PART_BLOCKS;                     // 2048
    const int conv_blocks = (out_size / 8 + 255) / 256;      // 3125
    partition_convert_kernel<<<part_blocks + conv_blocks, 256, 0, stream>>>(
        x, xb, out_size, src, dst, gcur, bdata, n_edges, part_blocks);

    const int agg_blocks = 2 * n_buckets;                    // 3126
    aggregate_kernel<<<agg_blocks, 256, 0, stream>>>(xb, gcur, bdata, hb, nullptr, n_nodes, 0);
    aggregate_kernel<<<agg_blocks, 256, 0, stream>>>(hb, gcur, bdata, nullptr, out, n_nodes, 1);
}

// Round 4
// 186.096 us; speedup vs baseline: 1.0923x; 1.0724x over previous
//
#include <hip/hip_runtime.h>
#include <hip/hip_bf16.h>

// LightGCN: two rounds of edge aggregation.
//   h[i]   = sum_{e: dst[e]==i} x[src[e]]
//   out[i] = sum_{e: dst[e]==i} relu(h)[src[e]]
//
// Round 16 (two-level partition -> CSR; lean gather aggregate):
//   Evidence R12-R15: partition time tracks the 1.25M scattered 4B stores
//   (each = L2 line allocate + fill + writeback ~128B of L2<->L3 fabric
//   traffic, invisible to HBM counters), NOT atomic count / block count /
//   WRITE_SIZE. So make every global write a sequential burst:
//     1) coarse tile-span partition into 782 bins of 128 nodes (spans ~10.5
//        edges; ~200K line-touches instead of 1.25M).
//     2) bin_sort: per-bin LDS counting sort by node, in-place coalesced
//        writeback + global nodeptr CSR (129 offsets/bin). No atomics.
//     3) aggregate: no filter/sort/LDS at all -- per-node [s0,s1) span of
//        src ids, batch-8 id loads + __shfl broadcast, 16B row gathers.
//   ReLU folded into pass-0 aggregate's bf16 write (elementwise, commutes).

#define N_FEAT    64
#define BIN_SHIFT 7
#define BIN_NODES 128
#define CAPBIN    2048             // edges per bin (mean 1600, +11 sigma)
#define NB_H      784              // >= n_bins (782)
#define GSTRIDE   16               // one gcur cursor per 64B line
#define TILE      8192
#define NPTR      (BIN_NODES + 1)  // nodeptr entries per bin

typedef unsigned int u32;
typedef unsigned short u16;
typedef __attribute__((ext_vector_type(8))) unsigned short u16x8;
typedef __attribute__((ext_vector_type(4))) unsigned int u32x4;
typedef __attribute__((ext_vector_type(2))) float f32x2;

__device__ inline u16 f2bf(float f) {          // RTNE
    u32 u = __builtin_bit_cast(u32, f);
    return (u16)((u + 0x7FFFu + ((u >> 16) & 1u)) >> 16);
}

// ---- pass 1: coarse partition (tile spans) + x->bf16 convert ----
__global__ __launch_bounds__(256) void partition_convert_kernel(
    const float* __restrict__ xf, u16* __restrict__ xb, int n_elems,
    const int* __restrict__ src, const int* __restrict__ dst,
    u32* __restrict__ gcur,        // [n_bins*GSTRIDE] padded cursors (zeroed)
    u32* __restrict__ cbdata,      // [n_bins*CAPBIN] packed (nid7<<17)|src
    int n_edges, int n_bins, int part_blocks)
{
    __shared__ u32 hist[NB_H];
    __shared__ u32 wcur[NB_H];

    const int tid = threadIdx.x;

    if ((int)blockIdx.x >= part_blocks) {      // ---- convert x -> bf16 ----
        int i = (((int)blockIdx.x - part_blocks) * 256 + tid) * 8;
        if (i < n_elems) {
            float4 a = *(const float4*)(xf + i);
            float4 b = *(const float4*)(xf + i + 4);
            u16x8 r;
            r[0]=f2bf(a.x); r[1]=f2bf(a.y); r[2]=f2bf(a.z); r[3]=f2bf(a.w);
            r[4]=f2bf(b.x); r[5]=f2bf(b.y); r[6]=f2bf(b.z); r[7]=f2bf(b.w);
            *(u16x8*)(xb + i) = r;
        }
        return;
    }

    const int tbase = (int)blockIdx.x * TILE;
    const int tend  = min(tbase + TILE, n_edges);

    for (int i = tid; i < NB_H; i += 256) hist[i] = 0;
    __syncthreads();

    for (int e = tbase + tid; e < tend; e += 256)      // pass A: count
        atomicAdd(&hist[(u32)dst[e] >> BIN_SHIFT], 1u);
    __syncthreads();

    // Reserve spans (rotated start to spread cursor-line contention).
    const int rot = (int)(((u32)blockIdx.x * 193u) % (u32)n_bins);
    for (int i = tid; i < n_bins; i += 256) {
        int b = i + rot; if (b >= n_bins) b -= n_bins;
        u32 h = hist[b];
        if (h) wcur[b] = atomicAdd(&gcur[b * GSTRIDE], h);
    }
    __syncthreads();

    for (int e = tbase + tid; e < tend; e += 256) {    // pass B: place
        int d = dst[e];                                 // L2-hot re-read
        int s = src[e];
        u32 b   = (u32)d >> BIN_SHIFT;
        u32 pos = atomicAdd(&wcur[b], 1u);
        if (pos < CAPBIN)
            cbdata[(size_t)b * CAPBIN + pos] =
                ((u32)(d & (BIN_NODES - 1)) << 17) | (u32)s;
    }
}

// ---- pass 2: per-bin LDS counting sort by node; in-place writeback + CSR ----
__global__ __launch_bounds__(256) void bin_sort_kernel(
    u32* __restrict__ cbdata,          // in: (nid7<<17)|src   out: src (sorted)
    const u32* __restrict__ gcur,
    u32* __restrict__ nodeptr,         // [n_bins*NPTR] absolute offsets
    int n_bins)
{
    __shared__ u32 hist[BIN_NODES];
    __shared__ u32 ptrs[NPTR];
    __shared__ u32 lpos[BIN_NODES];
    __shared__ u32 sl[CAPBIN];         // 8 KB staging

    const int tid = threadIdx.x;
    const int bin = blockIdx.x;
    if (bin >= n_bins) return;

    if (tid < BIN_NODES) { hist[tid] = 0; lpos[tid] = 0; }
    __syncthreads();

    int cnt = (int)gcur[bin * GSTRIDE];
    if (cnt > CAPBIN) cnt = CAPBIN;
    u32* bd = cbdata + (size_t)bin * CAPBIN;

    for (int j = tid; j < cnt; j += 256)               // count
        atomicAdd(&hist[bd[j] >> 17], 1u);
    __syncthreads();

    if (tid < 64) {                    // wave 0: scan 128 counters (2/lane)
        u32 a = hist[2 * tid], b = hist[2 * tid + 1];
        u32 s = a + b;
        #pragma unroll
        for (int d = 1; d < 64; d <<= 1) {
            u32 o = __shfl_up(s, d);
            if (tid >= d) s += o;
        }
        ptrs[2 * tid]     = s - a - b;
        ptrs[2 * tid + 1] = s - b;
        if (tid == 63) ptrs[BIN_NODES] = s;
    }
    __syncthreads();

    for (int j = tid; j < cnt; j += 256) {             // place into LDS
        u32 p   = bd[j];
        u32 nid = p >> 17;
        u32 pos = ptrs[nid] + atomicAdd(&lpos[nid], 1u);
        sl[pos] = p & 0x1FFFFu;
    }
    __syncthreads();

    const u32 base = (u32)bin * CAPBIN;
    for (int j = tid; j < cnt; j += 256)               // coalesced writeback
        bd[j] = sl[j];
    if (tid < NPTR)
        nodeptr[(size_t)bin * NPTR + tid] = base + ptrs[tid];
}

// ---- aggregate: one 8-lane group per node, CSR spans, no LDS ----
// pass 0: out_bf[node] = bf16(relu(sum))   pass 1: out_f[node] = sum (fp32)
__global__ __launch_bounds__(256) void aggregate_kernel(
    const u16* __restrict__ xin,
    const u32* __restrict__ csorted,   // sorted src ids
    const u32* __restrict__ nodeptr,
    u16* __restrict__ out_bf,
    float* __restrict__ out_f,
    int n_nodes, int pass)
{
    const int tid  = threadIdx.x;
    const int B    = blockIdx.x >> 1;
    const int half = blockIdx.x & 1;

    const int w    = tid >> 6;
    const int lane = tid & 63;
    const int grp  = lane >> 3;
    const int sub  = lane & 7;           // 16B chunk of the 128B bf16 row
    const char* xc = (const char*)xin;

    const int nl   = w * 8 + grp;        // 0..31
    const int node = B * 64 + half * 32 + nl;

    const int bin = node >> BIN_SHIFT;
    const int nid = node & (BIN_NODES - 1);
    const int s0  = (int)nodeptr[(size_t)bin * NPTR + nid];
    const int s1  = (int)nodeptr[(size_t)bin * NPTR + nid + 1];

    f32x2 a0={0.f,0.f}, a1={0.f,0.f}, a2={0.f,0.f}, a3={0.f,0.f};

    // Batch-8 id loads (one coalesced load per 8 edges), shfl-broadcast.
    for (int jb = s0; jb < s1; jb += 8) {
        u32 myid = 0;
        if (jb + sub < s1) myid = csorted[jb + sub];
        const int m = min(8, s1 - jb);
        #pragma unroll 1
        for (int k = 0; k < m; ++k) {
            u32 s = (u32)__shfl((int)myid, (lane & 56) + k, 64);
            u32x4 v = *(const u32x4*)(xc + ((size_t)s << 7) + (sub << 4));
            a0 += (f32x2){ __builtin_bit_cast(float, v[0] << 16),
                           __builtin_bit_cast(float, v[0] & 0xFFFF0000u) };
            a1 += (f32x2){ __builtin_bit_cast(float, v[1] << 16),
                           __builtin_bit_cast(float, v[1] & 0xFFFF0000u) };
            a2 += (f32x2){ __builtin_bit_cast(float, v[2] << 16),
                           __builtin_bit_cast(float, v[2] & 0xFFFF0000u) };
            a3 += (f32x2){ __builtin_bit_cast(float, v[3] << 16),
                           __builtin_bit_cast(float, v[3] & 0xFFFF0000u) };
        }
    }

    if (node < n_nodes) {
        if (pass == 0) {                 // 64 lanes x 16B: 8 bf16 rows, relu'd
            u16x8 o;
            o[0]=f2bf(fmaxf(a0.x,0.f)); o[1]=f2bf(fmaxf(a0.y,0.f));
            o[2]=f2bf(fmaxf(a1.x,0.f)); o[3]=f2bf(fmaxf(a1.y,0.f));
            o[4]=f2bf(fmaxf(a2.x,0.f)); o[5]=f2bf(fmaxf(a2.y,0.f));
            o[6]=f2bf(fmaxf(a3.x,0.f)); o[7]=f2bf(fmaxf(a3.y,0.f));
            *(u16x8*)(out_bf + (size_t)node * N_FEAT + sub * 8) = o;
        } else {                         // 64 lanes x 32B: 8 fp32 rows
            float* dp = out_f + (size_t)node * N_FEAT + sub * 8;
            *(float4*)dp       = (float4){a0.x, a0.y, a1.x, a1.y};
            *(float4*)(dp + 4) = (float4){a2.x, a2.y, a3.x, a3.y};
        }
    }
}

extern "C" void kernel_launch(void* const* d_in, const int* in_sizes, int n_in,
                              void* d_out, int out_size, void* d_ws, size_t ws_size,
                              hipStream_t stream) {
    const float* x          = (const float*)d_in[0];
    const int*   edge_index = (const int*)d_in[1];

    const int n_edges = in_sizes[1] / 2;          // (2, N_EDGES) row-major
    const int* src = edge_index;                  // row 0
    const int* dst = edge_index + n_edges;        // row 1

    const int n_nodes = out_size / N_FEAT;                      // 100000
    const int n_bins  = (n_nodes + BIN_NODES - 1) >> BIN_SHIFT; // 782
    float* out = (float*)d_out;

    const size_t xb_bytes    = (size_t)out_size * sizeof(u16);             // 12.8 MB
    const size_t hb_bytes    = (size_t)out_size * sizeof(u16);             // 12.8 MB
    const size_t cb_bytes    = (size_t)n_bins * CAPBIN * sizeof(u32);      // 6.4 MB
    const size_t np_bytes    = (size_t)n_bins * NPTR * sizeof(u32);        // 0.4 MB
    const size_t gcur_bytes  = (size_t)NB_H * GSTRIDE * sizeof(u32);       // 50 KB

    char* w = (char*)d_ws;
    u16* xb      = (u16*)w;              w += xb_bytes;
    u16* hb      = (u16*)w;              w += hb_bytes;
    u32* cbdata  = (u32*)w;              w += cb_bytes;
    u32* nodeptr = (u32*)w;              w += np_bytes;
    u32* gcur    = (u32*)w;

    hipMemsetAsync(gcur, 0, gcur_bytes, stream);

    const int part_blocks = (n_edges + TILE - 1) / TILE;     // 153
    const int conv_blocks = (out_size / 8 + 255) / 256;      // 3125
    partition_convert_kernel<<<part_blocks + conv_blocks, 256, 0, stream>>>(
        x, xb, out_size, src, dst, gcur, cbdata, n_edges, n_bins, part_blocks);

    bin_sort_kernel<<<n_bins, 256, 0, stream>>>(cbdata, gcur, nodeptr, n_bins);

    const int agg_blocks = 2 * ((n_nodes + 63) / 64);        // 3126
    aggregate_kernel<<<agg_blocks, 256, 0, stream>>>(xb, cbdata, nodeptr, hb, nullptr, n_nodes, 0);
    aggregate_kernel<<<agg_blocks, 256, 0, stream>>>(hb, cbdata, nodeptr, nullptr, out, n_nodes, 1);
}

// Round 5
// 170.231 us; speedup vs baseline: 1.1941x; 1.0932x over previous
//
#include <hip/hip_runtime.h>
#include <hip/hip_bf16.h>

// LightGCN: two rounds of edge aggregation.
//   h[i]   = sum_{e: dst[e]==i} x[src[e]]
//   out[i] = sum_{e: dst[e]==i} relu(h)[src[e]]
//
// Round 17 (LDS-sorted tile partition -> run-coalesced writes):
//   R12-R16 invariant: partition time (~46-55us) tracks the 1.25M per-edge
//   scattered 4B stores (64 lines touched per 64-lane store instr; each
//   line-touch = L2 allocate/fill/WB fabric traffic, invisible to HBM
//   counters). Spans alone don't fix it -- edges were still written in
//   arrival order. Fix: counting-sort each 4096-edge tile ENTIRELY IN LDS
//   (hist -> scan -> place + binid), reserve spans per (tile,bin), then
//   write the sorted buffer linearly: consecutive j in the same bin go to
//   consecutive global addresses -> a wave's store covers ~5-edge runs,
//   ~12 line touches instead of 64 (1.25M -> ~250K total).
//   - bin_sort: per-bin LDS counting sort by node -> CSR. Unchanged (R16).
//   - aggregate: no LDS; per-node CSR span, batch-8 id loads + shfl
//     broadcast, 16B row gathers. Unchanged (R16).
//   ReLU folded into pass-0 aggregate's bf16 write (elementwise, commutes).

#define N_FEAT    64
#define BIN_SHIFT 7
#define BIN_NODES 128
#define CAPBIN    2048             // edges per bin (mean 1600, +11 sigma)
#define NB_H      784              // >= n_bins (782)
#define NSCAN     1024             // padded hist size for the 4-per-thread scan
#define GSTRIDE   16               // one gcur cursor per 64B line
#define TILE      4096
#define NPTR      (BIN_NODES + 1)  // nodeptr entries per bin

typedef unsigned int u32;
typedef unsigned short u16;
typedef __attribute__((ext_vector_type(8))) unsigned short u16x8;
typedef __attribute__((ext_vector_type(4))) unsigned int u32x4;
typedef __attribute__((ext_vector_type(2))) float f32x2;

__device__ inline u16 f2bf(float f) {          // RTNE
    u32 u = __builtin_bit_cast(u32, f);
    return (u16)((u + 0x7FFFu + ((u >> 16) & 1u)) >> 16);
}

// ---- pass 1: LDS-sorted tile partition + x->bf16 convert ----
__global__ __launch_bounds__(256) void partition_convert_kernel(
    const float* __restrict__ xf, u16* __restrict__ xb, int n_elems,
    const int* __restrict__ src, const int* __restrict__ dst,
    u32* __restrict__ gcur,        // [n_bins*GSTRIDE] padded cursors (zeroed)
    u32* __restrict__ cbdata,      // [n_bins*CAPBIN] packed (nid7<<17)|src
    int n_edges, int n_bins, int part_blocks)
{
    __shared__ u32 hist[NSCAN];        // 4 KB
    __shared__ u32 starts[NSCAN];      // 4 KB (tile-local exclusive prefix)
    __shared__ u32 lpos[NSCAN];        // 4 KB
    __shared__ u32 wcur[NB_H];         // 3.1 KB (global span base per bin)
    __shared__ u32 sortbuf[TILE];      // 16 KB
    __shared__ u16 binid[TILE];        // 8 KB
    __shared__ u32 wsum[4];

    const int tid = threadIdx.x;

    if ((int)blockIdx.x >= part_blocks) {      // ---- convert x -> bf16 ----
        int i = (((int)blockIdx.x - part_blocks) * 256 + tid) * 8;
        if (i < n_elems) {
            float4 a = *(const float4*)(xf + i);
            float4 b = *(const float4*)(xf + i + 4);
            u16x8 r;
            r[0]=f2bf(a.x); r[1]=f2bf(a.y); r[2]=f2bf(a.z); r[3]=f2bf(a.w);
            r[4]=f2bf(b.x); r[5]=f2bf(b.y); r[6]=f2bf(b.z); r[7]=f2bf(b.w);
            *(u16x8*)(xb + i) = r;
        }
        return;
    }

    const int tbase = (int)blockIdx.x * TILE;
    const int tend  = min(tbase + TILE, n_edges);

    for (int i = tid; i < NSCAN; i += 256) { hist[i] = 0; lpos[i] = 0; }
    __syncthreads();

    for (int e = tbase + tid; e < tend; e += 256)      // pass A: count
        atomicAdd(&hist[(u32)dst[e] >> BIN_SHIFT], 1u);
    __syncthreads();

    // Tile-local exclusive scan of hist[0..NSCAN): 4 slots/thread + wave scan.
    {
        const int b0 = tid * 4;
        u32 h0 = hist[b0], h1 = hist[b0+1], h2 = hist[b0+2], h3 = hist[b0+3];
        u32 s  = h0 + h1 + h2 + h3;
        u32 inc = s;
        #pragma unroll
        for (int d = 1; d < 64; d <<= 1) {
            u32 o = __shfl_up(inc, d);
            if ((tid & 63) >= d) inc += o;
        }
        if ((tid & 63) == 63) wsum[tid >> 6] = inc;
        __syncthreads();
        u32 woff = 0;
        #pragma unroll
        for (int k = 0; k < 4; ++k) if (k < (tid >> 6)) woff += wsum[k];
        u32 excl = woff + inc - s;
        starts[b0]   = excl;
        starts[b0+1] = excl + h0;
        starts[b0+2] = excl + h0 + h1;
        starts[b0+3] = excl + h0 + h1 + h2;
    }
    __syncthreads();

    // Reserve global spans (rotated start to spread cursor-line contention).
    const int rot = (int)(((u32)blockIdx.x * 193u) % (u32)n_bins);
    for (int i = tid; i < n_bins; i += 256) {
        int b = i + rot; if (b >= n_bins) b -= n_bins;
        u32 h = hist[b];
        if (h) wcur[b] = atomicAdd(&gcur[b * GSTRIDE], h);
    }
    __syncthreads();

    for (int e = tbase + tid; e < tend; e += 256) {    // pass B: LDS place
        int d = dst[e];                                 // L2-hot re-read
        int s = src[e];
        u32 b   = (u32)d >> BIN_SHIFT;
        u32 pos = starts[b] + atomicAdd(&lpos[b], 1u);
        sortbuf[pos] = ((u32)(d & (BIN_NODES - 1)) << 17) | (u32)s;
        binid[pos]   = (u16)b;
    }
    __syncthreads();

    // pass C: linear sweep -> run-coalesced global writes.
    const int cnt = tend - tbase;
    for (int j = tid; j < cnt; j += 256) {
        u32 b   = binid[j];
        u32 rel = wcur[b] + ((u32)j - starts[b]);
        if (rel < CAPBIN)
            cbdata[(size_t)b * CAPBIN + rel] = sortbuf[j];
    }
}

// ---- pass 2: per-bin LDS counting sort by node; in-place writeback + CSR ----
__global__ __launch_bounds__(256) void bin_sort_kernel(
    u32* __restrict__ cbdata,          // in: (nid7<<17)|src   out: src (sorted)
    const u32* __restrict__ gcur,
    u32* __restrict__ nodeptr,         // [n_bins*NPTR] absolute offsets
    int n_bins)
{
    __shared__ u32 hist[BIN_NODES];
    __shared__ u32 ptrs[NPTR];
    __shared__ u32 lpos[BIN_NODES];
    __shared__ u32 sl[CAPBIN];         // 8 KB staging

    const int tid = threadIdx.x;
    const int bin = blockIdx.x;
    if (bin >= n_bins) return;

    if (tid < BIN_NODES) { hist[tid] = 0; lpos[tid] = 0; }
    __syncthreads();

    int cnt = (int)gcur[bin * GSTRIDE];
    if (cnt > CAPBIN) cnt = CAPBIN;
    u32* bd = cbdata + (size_t)bin * CAPBIN;

    for (int j = tid; j < cnt; j += 256)               // count
        atomicAdd(&hist[bd[j] >> 17], 1u);
    __syncthreads();

    if (tid < 64) {                    // wave 0: scan 128 counters (2/lane)
        u32 a = hist[2 * tid], b = hist[2 * tid + 1];
        u32 s = a + b;
        #pragma unroll
        for (int d = 1; d < 64; d <<= 1) {
            u32 o = __shfl_up(s, d);
            if (tid >= d) s += o;
        }
        ptrs[2 * tid]     = s - a - b;
        ptrs[2 * tid + 1] = s - b;
        if (tid == 63) ptrs[BIN_NODES] = s;
    }
    __syncthreads();

    for (int j = tid; j < cnt; j += 256) {             // place into LDS
        u32 p   = bd[j];
        u32 nid = p >> 17;
        u32 pos = ptrs[nid] + atomicAdd(&lpos[nid], 1u);
        sl[pos] = p & 0x1FFFFu;
    }
    __syncthreads();

    const u32 base = (u32)bin * CAPBIN;
    for (int j = tid; j < cnt; j += 256)               // coalesced writeback
        bd[j] = sl[j];
    if (tid < NPTR)
        nodeptr[(size_t)bin * NPTR + tid] = base + ptrs[tid];
}

// ---- aggregate: one 8-lane group per node, CSR spans, no LDS ----
// pass 0: out_bf[node] = bf16(relu(sum))   pass 1: out_f[node] = sum (fp32)
__global__ __launch_bounds__(256) void aggregate_kernel(
    const u16* __restrict__ xin,
    const u32* __restrict__ csorted,   // sorted src ids
    const u32* __restrict__ nodeptr,
    u16* __restrict__ out_bf,
    float* __restrict__ out_f,
    int n_nodes, int pass)
{
    const int tid  = threadIdx.x;
    const int B    = blockIdx.x >> 1;
    const int half = blockIdx.x & 1;

    const int w    = tid >> 6;
    const int lane = tid & 63;
    const int grp  = lane >> 3;
    const int sub  = lane & 7;           // 16B chunk of the 128B bf16 row
    const char* xc = (const char*)xin;

    const int nl   = w * 8 + grp;        // 0..31
    const int node = B * 64 + half * 32 + nl;

    const int bin = node >> BIN_SHIFT;
    const int nid = node & (BIN_NODES - 1);
    const int s0  = (int)nodeptr[(size_t)bin * NPTR + nid];
    const int s1  = (int)nodeptr[(size_t)bin * NPTR + nid + 1];

    f32x2 a0={0.f,0.f}, a1={0.f,0.f}, a2={0.f,0.f}, a3={0.f,0.f};

    // Batch-8 id loads (one coalesced load per 8 edges), shfl-broadcast.
    for (int jb = s0; jb < s1; jb += 8) {
        u32 myid = 0;
        if (jb + sub < s1) myid = csorted[jb + sub];
        const int m = min(8, s1 - jb);
        #pragma unroll 1
        for (int k = 0; k < m; ++k) {
            u32 s = (u32)__shfl((int)myid, (lane & 56) + k, 64);
            u32x4 v = *(const u32x4*)(xc + ((size_t)s << 7) + (sub << 4));
            a0 += (f32x2){ __builtin_bit_cast(float, v[0] << 16),
                           __builtin_bit_cast(float, v[0] & 0xFFFF0000u) };
            a1 += (f32x2){ __builtin_bit_cast(float, v[1] << 16),
                           __builtin_bit_cast(float, v[1] & 0xFFFF0000u) };
            a2 += (f32x2){ __builtin_bit_cast(float, v[2] << 16),
                           __builtin_bit_cast(float, v[2] & 0xFFFF0000u) };
            a3 += (f32x2){ __builtin_bit_cast(float, v[3] << 16),
                           __builtin_bit_cast(float, v[3] & 0xFFFF0000u) };
        }
    }

    if (node < n_nodes) {
        if (pass == 0) {                 // 64 lanes x 16B: 8 bf16 rows, relu'd
            u16x8 o;
            o[0]=f2bf(fmaxf(a0.x,0.f)); o[1]=f2bf(fmaxf(a0.y,0.f));
            o[2]=f2bf(fmaxf(a1.x,0.f)); o[3]=f2bf(fmaxf(a1.y,0.f));
            o[4]=f2bf(fmaxf(a2.x,0.f)); o[5]=f2bf(fmaxf(a2.y,0.f));
            o[6]=f2bf(fmaxf(a3.x,0.f)); o[7]=f2bf(fmaxf(a3.y,0.f));
            *(u16x8*)(out_bf + (size_t)node * N_FEAT + sub * 8) = o;
        } else {                         // 64 lanes x 32B: 8 fp32 rows
            float* dp = out_f + (size_t)node * N_FEAT + sub * 8;
            *(float4*)dp       = (float4){a0.x, a0.y, a1.x, a1.y};
            *(float4*)(dp + 4) = (float4){a2.x, a2.y, a3.x, a3.y};
        }
    }
}

extern "C" void kernel_launch(void* const* d_in, const int* in_sizes, int n_in,
                              void* d_out, int out_size, void* d_ws, size_t ws_size,
                              hipStream_t stream) {
    const float* x          = (const float*)d_in[0];
    const int*   edge_index = (const int*)d_in[1];

    const int n_edges = in_sizes[1] / 2;          // (2, N_EDGES) row-major
    const int* src = edge_index;                  // row 0
    const int* dst = edge_index + n_edges;        // row 1

    const int n_nodes = out_size / N_FEAT;                      // 100000
    const int n_bins  = (n_nodes + BIN_NODES - 1) >> BIN_SHIFT; // 782
    float* out = (float*)d_out;

    const size_t xb_bytes    = (size_t)out_size * sizeof(u16);             // 12.8 MB
    const size_t hb_bytes    = (size_t)out_size * sizeof(u16);             // 12.8 MB
    const size_t cb_bytes    = (size_t)n_bins * CAPBIN * sizeof(u32);      // 6.4 MB
    const size_t np_bytes    = (size_t)n_bins * NPTR * sizeof(u32);        // 0.4 MB
    const size_t gcur_bytes  = (size_t)NB_H * GSTRIDE * sizeof(u32);       // 50 KB

    char* w = (char*)d_ws;
    u16* xb      = (u16*)w;              w += xb_bytes;
    u16* hb      = (u16*)w;              w += hb_bytes;
    u32* cbdata  = (u32*)w;              w += cb_bytes;
    u32* nodeptr = (u32*)w;              w += np_bytes;
    u32* gcur    = (u32*)w;

    hipMemsetAsync(gcur, 0, gcur_bytes, stream);

    const int part_blocks = (n_edges + TILE - 1) / TILE;     // 306
    const int conv_blocks = (out_size / 8 + 255) / 256;      // 3125
    partition_convert_kernel<<<part_blocks + conv_blocks, 256, 0, stream>>>(
        x, xb, out_size, src, dst, gcur, cbdata, n_edges, n_bins, part_blocks);

    bin_sort_kernel<<<n_bins, 256, 0, stream>>>(cbdata, gcur, nodeptr, n_bins);

    const int agg_blocks = 2 * ((n_nodes + 63) / 64);        // 3126
    aggregate_kernel<<<agg_blocks, 256, 0, stream>>>(xb, cbdata, nodeptr, hb, nullptr, n_nodes, 0);
    aggregate_kernel<<<agg_blocks, 256, 0, stream>>>(hb, cbdata, nodeptr, nullptr, out, n_nodes, 1);
}